// Round 1
// 1689.980 us; speedup vs baseline: 1.1880x; 1.1880x over previous
//
#include <hip/hip_runtime.h>
#include <hip/hip_bf16.h>
#include <math.h>

// SparseMoE: B=4, L=2048 -> T=8192 tokens, D=1024, FFN=4096, E=8, topk=2.
// Inputs/outputs are fp32 on device (proved in R5 by runtime dtype bisect).
// Compute: bf16 MFMA (threshold is 2% of ref max; bf16 path measured absmax 3.9e-3).
#define T_TOKENS 8192
#define DM 1024
#define FFNDIM 4096
#define NE 8
#define CAP 8192

typedef __attribute__((ext_vector_type(8))) __bf16 bf16x8;
typedef __attribute__((ext_vector_type(4))) float f32x4;

__device__ __forceinline__ float gelu_exact(float v) {
    return 0.5f * v * (1.0f + erff(v * 0.70710678118654752440f));
}

union PK8 { __bf16 h[8]; uint4 v; };

// XCD-chunked bijective swizzle (m157; valid because all our grids have nwg%8==0).
// HW dispatch round-robins blockIdx across the 8 XCDs; this remap gives each XCD a
// CONTIGUOUS range of work ids, so blocks sharing a B-slice share one XCD's L2.
__device__ __forceinline__ int xcd_work_id(int nwg) {
    return (blockIdx.x & 7) * (nwg >> 3) + (blockIdx.x >> 3);
}

// ---------------- zero fp32 d_out + counters ----------------
__global__ __launch_bounds__(256) void zero_out_kernel(float* __restrict__ out,
                                                       int* __restrict__ counts) {
    size_t i = (size_t)blockIdx.x * 256 + threadIdx.x;   // 4096 blocks x 256 x 8 floats
    uint4 z = make_uint4(0u, 0u, 0u, 0u);
    uint4* p = (uint4*)out + i * 2;
    p[0] = z; p[1] = z;
    if (blockIdx.x == 0 && threadIdx.x < NE) counts[threadIdx.x] = 0;
}

// ---------------- router: fp32 logits, top-2 (first-index ties), 2-way softmax ----------------
__global__ __launch_bounds__(256) void router_kernel(
        const float* __restrict__ x, const float* __restrict__ gate_w,
        const float* __restrict__ gate_b, int* __restrict__ counts,
        int* __restrict__ idx_list, float* __restrict__ gate_list) {
    int wave = threadIdx.x >> 6, lane = threadIdx.x & 63;
    int tk = blockIdx.x * 4 + wave;                      // one wave per token
    const float* xr = x + (size_t)tk * DM;
    float acc[NE];
#pragma unroll
    for (int e = 0; e < NE; ++e) acc[e] = 0.f;
#pragma unroll
    for (int i = 0; i < DM / 64; ++i) {
        int d = i * 64 + lane;
        float xv = xr[d];
        f32x4 g0v = *(const f32x4*)(gate_w + d * NE);
        f32x4 g1v = *(const f32x4*)(gate_w + d * NE + 4);
#pragma unroll
        for (int e = 0; e < 4; ++e) { acc[e] += xv * g0v[e]; acc[4 + e] += xv * g1v[e]; }
    }
#pragma unroll
    for (int e = 0; e < NE; ++e) {
#pragma unroll
        for (int m = 32; m > 0; m >>= 1) acc[e] += __shfl_xor(acc[e], m, 64);
    }
    if (lane == 0) {
        float v0 = -INFINITY, v1 = -INFINITY;
        int i0 = 0, i1 = 0;
#pragma unroll
        for (int e = 0; e < NE; ++e) {
            float l = acc[e] + gate_b[e];
            if (l > v0) { v1 = v0; i1 = i0; v0 = l; i0 = e; }
            else if (l > v1) { v1 = l; i1 = e; }
        }
        float g0 = 1.f / (1.f + expf(v1 - v0));          // softmax over {v0,v1}, v0 = max
        float g1 = 1.f - g0;
        int p0 = atomicAdd(&counts[i0], 1);
        idx_list[i0 * CAP + p0] = tk;
        gate_list[i0 * CAP + p0] = g0;
        int p1 = atomicAdd(&counts[i1], 1);
        idx_list[i1 * CAP + p1] = tk;
        gate_list[i1 * CAP + p1] = g1;
    }
}

// ---------------- scan: pbase[e] = 128-aligned prefix; pbase[8] = padded total ----------------
__global__ void scan_kernel(const int* __restrict__ counts, int* __restrict__ pbase) {
    if (threadIdx.x == 0 && blockIdx.x == 0) {
        int s = 0;
        for (int e = 0; e < NE; ++e) {
            pbase[e] = s;
            s += (counts[e] + 127) & ~127;
        }
        pbase[NE] = s;
    }
}

__device__ __forceinline__ int find_expert(const int* pbase, int slot_tile) {
    int e = 0;
#pragma unroll
    for (int k = 0; k < NE - 1; ++k)
        if (pbase[k + 1] <= slot_tile) e = k + 1;
    return e;
}

// ---------------- gemm1: h[chunk-local slot][0..4095] = gelu(x[tok] @ w1[e] + b1[e]) ----------------
// 1-D grid = MT*32 (MT = S/128), XCD-swizzled, work order mtile-fastest so blocks
// sharing the same (e, nt) B-slice are contiguous on one XCD. K = DM = 1024.
__global__ __launch_bounds__(256, 3) void gemm1_kernel(
        const float* __restrict__ x, const float* __restrict__ w1,
        const float* __restrict__ b1, const int* __restrict__ counts,
        const int* __restrict__ pbase, const int* __restrict__ idx_list,
        __bf16* __restrict__ h, int chunk_start) {
    __shared__ __bf16 Alds[128 * 72];   // [m][k], stride 72: b128-read friendly
    __shared__ __bf16 Btld[128 * 72];   // [n][k] TRANSPOSED: b128-read friendly

    int nwg = gridDim.x;
    int wid = xcd_work_id(nwg);
    int MT  = nwg >> 5;                 // NT = 32
    int mtl = wid % MT;
    int nt  = wid / MT;

    int slot_tile = chunk_start + mtl * 128;
    if (slot_tile >= pbase[NE]) return;
    int e = find_expert(pbase, slot_tile);
    int cnt = counts[e];
    int loc_tile = slot_tile - pbase[e];
    if (loc_tile >= cnt) return;                         // pure-padding tile

    int t = threadIdx.x;
    // A gather staging: 2 threads/row, 32 fp32 each -> 32 bf16
    int am = t >> 1, ahalf = (t & 1) * 32;
    int localc = loc_tile + am; if (localc > cnt - 1) localc = cnt - 1;
    int tok = idx_list[e * CAP + localc];
    const float* arow = x + (size_t)tok * DM + ahalf;
    __bf16* adst = Alds + am * 72 + ahalf;
    // B transpose staging: thread covers 8k x 4n patch
    int k0 = (t & 7) * 8;
    int n0 = (t >> 3) * 4;
    const float* bbase = w1 + (size_t)e * DM * FFNDIM + (size_t)k0 * FFNDIM + nt * 128 + n0;
    __bf16* bdst = Btld + n0 * 72 + k0;

    int lane = t & 63, wave = t >> 6;
    int wm = (wave >> 1) * 64, wn = (wave & 1) * 64;     // 2x2 waves of 64x64
    int l15 = lane & 15, quad = lane >> 4;

    f32x4 acc[4][4];
#pragma unroll
    for (int i = 0; i < 4; ++i)
#pragma unroll
        for (int j = 0; j < 4; ++j) acc[i][j] = f32x4{0.f, 0.f, 0.f, 0.f};

    for (int kb = 0; kb < DM; kb += 64) {
        // global loads (fp32)
        f32x4 av[8], bv[8];
        const f32x4* ap = (const f32x4*)(arow + kb);
        const float* bp = bbase + (size_t)kb * FFNDIM;
#pragma unroll
        for (int q = 0; q < 8; ++q) av[q] = ap[q];
#pragma unroll
        for (int kk = 0; kk < 8; ++kk) bv[kk] = *(const f32x4*)(bp + (size_t)kk * FFNDIM);
        // convert to packed bf16 BEFORE the barrier (drops fp32 liveness)
        uint4 apk[4], bpk[4];
#pragma unroll
        for (int q = 0; q < 4; ++q) {
            PK8 u;
#pragma unroll
            for (int w = 0; w < 4; ++w) {
                u.h[w]     = (__bf16)av[2 * q][w];
                u.h[4 + w] = (__bf16)av[2 * q + 1][w];
            }
            apk[q] = u.v;
        }
#pragma unroll
        for (int j = 0; j < 4; ++j) {
            PK8 u;
#pragma unroll
            for (int kk = 0; kk < 8; ++kk) u.h[kk] = (__bf16)bv[kk][j];
            bpk[j] = u.v;
        }
        __syncthreads();                                 // prev iter's LDS reads done
#pragma unroll
        for (int q = 0; q < 4; ++q) *(uint4*)(adst + q * 8) = apk[q];
#pragma unroll
        for (int j = 0; j < 4; ++j) *(uint4*)(bdst + j * 72) = bpk[j];
        __syncthreads();
#pragma unroll
        for (int ks = 0; ks < 2; ++ks) {
            int ko = ks * 32 + quad * 8;
            bf16x8 af[4], bf[4];
#pragma unroll
            for (int i = 0; i < 4; ++i)
                af[i] = *(const bf16x8*)(Alds + (wm + i * 16 + l15) * 72 + ko);
#pragma unroll
            for (int j = 0; j < 4; ++j)
                bf[j] = *(const bf16x8*)(Btld + (wn + j * 16 + l15) * 72 + ko);
#pragma unroll
            for (int i = 0; i < 4; ++i)
#pragma unroll
                for (int j = 0; j < 4; ++j)
                    acc[i][j] = __builtin_amdgcn_mfma_f32_16x16x32_bf16(
                        af[i], bf[j], acc[i][j], 0, 0, 0);
        }
    }
    float bias[4];
#pragma unroll
    for (int j = 0; j < 4; ++j)
        bias[j] = b1[(size_t)e * FFNDIM + nt * 128 + wn + j * 16 + l15];
#pragma unroll
    for (int i = 0; i < 4; ++i) {
#pragma unroll
        for (int r = 0; r < 4; ++r) {
            int rowl = wm + i * 16 + quad * 4 + r;       // C/D: col=lane&15, row=quad*4+reg
            if (loc_tile + rowl < cnt) {
                size_t hoff = (size_t)(mtl * 128 + rowl) * FFNDIM + nt * 128;
#pragma unroll
                for (int j = 0; j < 4; ++j) {
                    float v = acc[i][j][r] + bias[j];
                    h[hoff + wn + j * 16 + l15] = (__bf16)gelu_exact(v);
                }
            }
        }
    }
}

// ---------------- gemm2: out[tok] += gate*(h_slot @ w2[e] slice + b2 on ksplit0) ----------------
// 1-D grid = MT*8*KSP, XCD-swizzled, mtile-fastest. kspan = 4096/KSP per block.
// KSP is runtime-tiered: fewer K-splits => fewer device-scope atomicAdds per out element.
__global__ __launch_bounds__(256, 3) void gemm2_kernel(
        const __bf16* __restrict__ h, const float* __restrict__ w2,
        const float* __restrict__ b2, const int* __restrict__ counts,
        const int* __restrict__ pbase, const int* __restrict__ idx_list,
        const float* __restrict__ gate_list, float* __restrict__ out,
        int ksp_count, int chunk_start) {
    __shared__ __bf16 Alds[128 * 72];
    __shared__ __bf16 Btld[128 * 72];

    int nwg = gridDim.x;
    int wid = xcd_work_id(nwg);
    int MT  = nwg / (8 * ksp_count);
    int mtl = wid % MT;
    int nt  = (wid / MT) & 7;
    int ksp = wid / (MT * 8);
    int kspan = FFNDIM / ksp_count;

    int slot_tile = chunk_start + mtl * 128;
    if (slot_tile >= pbase[NE]) return;
    int e = find_expert(pbase, slot_tile);
    int cnt = counts[e];
    int loc_tile = slot_tile - pbase[e];
    if (loc_tile >= cnt) return;

    int t = threadIdx.x;
    int am = t >> 1, ahalf = (t & 1) * 32;
    int localc = loc_tile + am; if (localc > cnt - 1) localc = cnt - 1;
    int hrow = (pbase[e] + localc) - chunk_start;        // chunk-local; always in [0,S)
    const __bf16* arow = h + (size_t)hrow * FFNDIM + ksp * kspan + ahalf;
    __bf16* adst = Alds + am * 72 + ahalf;
    int k0 = (t & 7) * 8;
    int n0 = (t >> 3) * 4;
    const float* bbase = w2 + (size_t)e * FFNDIM * DM + (size_t)(ksp * kspan + k0) * DM
                         + nt * 128 + n0;
    __bf16* bdst = Btld + n0 * 72 + k0;

    int lane = t & 63, wave = t >> 6;
    int wm = (wave >> 1) * 64, wn = (wave & 1) * 64;
    int l15 = lane & 15, quad = lane >> 4;

    f32x4 acc[4][4];
#pragma unroll
    for (int i = 0; i < 4; ++i)
#pragma unroll
        for (int j = 0; j < 4; ++j) acc[i][j] = f32x4{0.f, 0.f, 0.f, 0.f};

    for (int kb = 0; kb < kspan; kb += 64) {
        uint4 apk[4];
        f32x4 bv[8];
        const uint4* ap = (const uint4*)(arow + kb);     // h is bf16 already
        const float* bp = bbase + (size_t)kb * DM;
#pragma unroll
        for (int q = 0; q < 4; ++q) apk[q] = ap[q];
#pragma unroll
        for (int kk = 0; kk < 8; ++kk) bv[kk] = *(const f32x4*)(bp + (size_t)kk * DM);
        uint4 bpk[4];
#pragma unroll
        for (int j = 0; j < 4; ++j) {
            PK8 u;
#pragma unroll
            for (int kk = 0; kk < 8; ++kk) u.h[kk] = (__bf16)bv[kk][j];
            bpk[j] = u.v;
        }
        __syncthreads();
#pragma unroll
        for (int q = 0; q < 4; ++q) *(uint4*)(adst + q * 8) = apk[q];
#pragma unroll
        for (int j = 0; j < 4; ++j) *(uint4*)(bdst + j * 72) = bpk[j];
        __syncthreads();
#pragma unroll
        for (int ks = 0; ks < 2; ++ks) {
            int ko = ks * 32 + quad * 8;
            bf16x8 af[4], bf[4];
#pragma unroll
            for (int i = 0; i < 4; ++i)
                af[i] = *(const bf16x8*)(Alds + (wm + i * 16 + l15) * 72 + ko);
#pragma unroll
            for (int j = 0; j < 4; ++j)
                bf[j] = *(const bf16x8*)(Btld + (wn + j * 16 + l15) * 72 + ko);
#pragma unroll
            for (int i = 0; i < 4; ++i)
#pragma unroll
                for (int j = 0; j < 4; ++j)
                    acc[i][j] = __builtin_amdgcn_mfma_f32_16x16x32_bf16(
                        af[i], bf[j], acc[i][j], 0, 0, 0);
        }
    }
    float b2v[4];
#pragma unroll
    for (int j = 0; j < 4; ++j)
        b2v[j] = b2[(size_t)e * DM + nt * 128 + wn + j * 16 + l15];
#pragma unroll
    for (int i = 0; i < 4; ++i) {
#pragma unroll
        for (int r = 0; r < 4; ++r) {
            int rowl = wm + i * 16 + quad * 4 + r;
            int local = loc_tile + rowl;
            if (local < cnt) {
                int tok = idx_list[e * CAP + local];
                float g = gate_list[e * CAP + local];
                float* orow = out + (size_t)tok * DM + nt * 128;
#pragma unroll
                for (int j = 0; j < 4; ++j) {
                    float v = acc[i][j][r];
                    if (ksp == 0) v += b2v[j];           // b2 exactly once per (token,expert)
                    atomicAdd(orow + wn + j * 16 + l15, g * v);
                }
            }
        }
    }
}

extern "C" void kernel_launch(void* const* d_in, const int* in_sizes, int n_in,
                              void* d_out, int out_size, void* d_ws, size_t ws_size,
                              hipStream_t stream) {
    const float* x      = (const float*)d_in[0];
    const float* gate_w = (const float*)d_in[1];
    const float* gate_b = (const float*)d_in[2];
    const float* w1     = (const float*)d_in[3];
    const float* b1     = (const float*)d_in[4];
    const float* w2     = (const float*)d_in[5];
    const float* b2     = (const float*)d_in[6];
    float* out = (float*)d_out;

    // ws: [counts 64B][pbase 64B][idx 256KiB][gate 256KiB][hbuf S*4096*2B]
    char* wsb = (char*)d_ws;
    int*   counts   = (int*)wsb;
    int*   pbase    = (int*)(wsb + 64);
    int*   idx_list = (int*)(wsb + 128);
    float* gate_lst = (float*)(wsb + 128 + 262144);
    __bf16* hbuf    = (__bf16*)(wsb + 524416);
    const size_t fixed = 524416;

    // Padded slot total <= 16384 + 8*127 = 17400 <= 17408.
    // Tiers: larger S => fewer chunks (less weight re-read across chunk boundaries)
    // and smaller KSP (fewer atomicAdds per out element). KSP sized to keep
    // gemm2 >= ~2 blocks/CU.
    int S, NCH, KSP;
    if      (ws_size >= fixed + 17408ull * 8192) { S = 17408; NCH = 1;  KSP = 1; }
    else if (ws_size >= fixed + 4096ull * 8192)  { S = 4096;  NCH = 5;  KSP = 2; }
    else if (ws_size >= fixed + 2048ull * 8192)  { S = 2048;  NCH = 9;  KSP = 4; }
    else if (ws_size >= fixed + 1024ull * 8192)  { S = 1024;  NCH = 17; KSP = 4; }
    else                                         { S = 512;   NCH = 34; KSP = 4; }

    zero_out_kernel<<<4096, 256, 0, stream>>>(out, counts);
    router_kernel<<<2048, 256, 0, stream>>>(x, gate_w, gate_b, counts, idx_list, gate_lst);
    scan_kernel<<<1, 64, 0, stream>>>(counts, pbase);
    int MT = S / 128;
    for (int c = 0; c < NCH; ++c) {
        gemm1_kernel<<<dim3(MT * 32), 256, 0, stream>>>(x, w1, b1, counts, pbase,
                                                        idx_list, hbuf, c * S);
        gemm2_kernel<<<dim3(MT * 8 * KSP), 256, 0, stream>>>(hbuf, w2, b2, counts, pbase,
                                                             idx_list, gate_lst, out,
                                                             KSP, c * S);
    }
}

// Round 2
// 1112.050 us; speedup vs baseline: 1.8055x; 1.5197x over previous
//
#include <hip/hip_runtime.h>
#include <hip/hip_bf16.h>
#include <math.h>
#include <stdint.h>

// SparseMoE: B=4, L=2048 -> T=8192 tokens, D=1024, FFN=4096, E=8, topk=2.
// Inputs/outputs fp32 on device. Compute bf16 MFMA.
// R2: m97-structure GEMM cores: pre-transposed bf16 weights + global_load_lds(16B)
//     staging with both-sides XOR swizzle; ybuf+combine kills out atomics.
#define T_TOKENS 8192
#define DM 1024
#define FFNDIM 4096
#define NE 8
#define CAP 8192

typedef __attribute__((ext_vector_type(8))) __bf16 bf16x8;
typedef __attribute__((ext_vector_type(4))) __bf16 bf16x4;
typedef __attribute__((ext_vector_type(4))) float f32x4;

__device__ __forceinline__ float gelu_exact(float v) {
    return 0.5f * v * (1.0f + erff(v * 0.70710678118654752440f));
}

union PK8 { __bf16 h[8]; uint4 v; };

// 16B global -> LDS DMA. LDS dest must be WAVE-UNIFORM base; HW writes base+lane*16.
// Global src is per-lane (this is how the XOR swizzle gets into a linear LDS tile).
__device__ __forceinline__ void gload16(const void* g, void* l) {
    __builtin_amdgcn_global_load_lds(
        (const __attribute__((address_space(1))) uint32_t*)g,
        (__attribute__((address_space(3))) uint32_t*)l, 16, 0, 0);
}

// ---------------- tiny zero kernels ----------------
__global__ void zero_counts_kernel(int* __restrict__ counts) {
    if (threadIdx.x < NE) counts[threadIdx.x] = 0;
}

__global__ __launch_bounds__(256) void zero_out_kernel(float* __restrict__ out,
                                                       int* __restrict__ counts) {
    size_t i = (size_t)blockIdx.x * 256 + threadIdx.x;   // 4096 blocks x 256 x 8 floats
    uint4 z = make_uint4(0u, 0u, 0u, 0u);
    uint4* p = (uint4*)out + i * 2;
    p[0] = z; p[1] = z;
    if (blockIdx.x == 0 && threadIdx.x < NE) counts[threadIdx.x] = 0;
}

// ---------------- prepass: w [E][K][N] f32 -> wt [E][N][K] bf16 (64x64 LDS tiles) ----------------
__global__ __launch_bounds__(256) void transpose_cvt_kernel(
        const float* __restrict__ w, __bf16* __restrict__ wt, int K, int N) {
    __shared__ __bf16 tile[64][72];
    int ntb = blockIdx.x, ktb = blockIdx.y, e = blockIdx.z;
    const float* src = w + ((size_t)e * K + (size_t)ktb * 64) * N + ntb * 64;
    int t = threadIdx.x;
    int tx = t & 15, ty = t >> 4;
#pragma unroll
    for (int rr = 0; rr < 4; ++rr) {
        int r = ty + rr * 16;
        f32x4 v = *(const f32x4*)(src + (size_t)r * N + tx * 4);
#pragma unroll
        for (int j = 0; j < 4; ++j) tile[tx * 4 + j][r] = (__bf16)v[j];
    }
    __syncthreads();
    int ow = t & 7, oy = t >> 3;
#pragma unroll
    for (int rr = 0; rr < 2; ++rr) {
        int n = oy + rr * 32;
        uint4 val = *(const uint4*)&tile[n][ow * 8];
        *(uint4*)(wt + ((size_t)e * N + (size_t)ntb * 64 + n) * K
                  + (size_t)ktb * 64 + ow * 8) = val;
    }
}

// ---------------- router: fp32 logits, top-2, 2-way softmax; emits per-token pack ----------------
__global__ __launch_bounds__(256) void router_kernel(
        const float* __restrict__ x, const float* __restrict__ gate_w,
        const float* __restrict__ gate_b, int* __restrict__ counts,
        int* __restrict__ idx_list, float* __restrict__ gate_list,
        uint32_t* __restrict__ pack) {
    int wave = threadIdx.x >> 6, lane = threadIdx.x & 63;
    int tk = blockIdx.x * 4 + wave;                      // one wave per token
    const float* xr = x + (size_t)tk * DM;
    float acc[NE];
#pragma unroll
    for (int e = 0; e < NE; ++e) acc[e] = 0.f;
#pragma unroll
    for (int i = 0; i < DM / 64; ++i) {
        int d = i * 64 + lane;
        float xv = xr[d];
        f32x4 g0v = *(const f32x4*)(gate_w + d * NE);
        f32x4 g1v = *(const f32x4*)(gate_w + d * NE + 4);
#pragma unroll
        for (int e = 0; e < 4; ++e) { acc[e] += xv * g0v[e]; acc[4 + e] += xv * g1v[e]; }
    }
#pragma unroll
    for (int e = 0; e < NE; ++e) {
#pragma unroll
        for (int m = 32; m > 0; m >>= 1) acc[e] += __shfl_xor(acc[e], m, 64);
    }
    if (lane == 0) {
        float v0 = -INFINITY, v1 = -INFINITY;
        int i0 = 0, i1 = 0;
#pragma unroll
        for (int e = 0; e < NE; ++e) {
            float l = acc[e] + gate_b[e];
            if (l > v0) { v1 = v0; i1 = i0; v0 = l; i0 = e; }
            else if (l > v1) { v1 = l; i1 = e; }
        }
        float g0 = 1.f / (1.f + expf(v1 - v0));
        float g1 = 1.f - g0;
        int p0 = atomicAdd(&counts[i0], 1);
        idx_list[i0 * CAP + p0] = tk;
        gate_list[i0 * CAP + p0] = g0;
        int p1 = atomicAdd(&counts[i1], 1);
        idx_list[i1 * CAP + p1] = tk;
        gate_list[i1 * CAP + p1] = g1;
        pack[tk] = ((uint32_t)((i0 << 13) | p0) << 16) | (uint32_t)((i1 << 13) | p1);
    }
}

// ---------------- scan ----------------
__global__ void scan_kernel(const int* __restrict__ counts, int* __restrict__ pbase) {
    if (threadIdx.x == 0 && blockIdx.x == 0) {
        int s = 0;
        for (int e = 0; e < NE; ++e) { pbase[e] = s; s += (counts[e] + 127) & ~127; }
        pbase[NE] = s;
    }
}

__device__ __forceinline__ int find_expert(const int* pbase, int slot_tile) {
    int e = 0;
#pragma unroll
    for (int k = 0; k < NE - 1; ++k)
        if (pbase[k + 1] <= slot_tile) e = k + 1;
    return e;
}

// ---------------- gemm1: h = gelu(x[tok] @ w1[e] + b1[e]) ----------------
// A: reg-staged gather (fp32->bf16), LDS stride 72 (proven). B: gload_lds from w1t
// [e][n][k] bf16, linear [128][64] LDS with XOR chunk swizzle (source-side + read-side).
__global__ __launch_bounds__(256, 4) void gemm1_kernel(
        const float* __restrict__ x, const __bf16* __restrict__ w1t,
        const float* __restrict__ b1, const int* __restrict__ counts,
        const int* __restrict__ pbase, const int* __restrict__ idx_list,
        __bf16* __restrict__ h, int chunk_start) {
    __shared__ __bf16 Alds[128 * 72];
    __shared__ __bf16 Blds[128 * 64];

    int nwg = gridDim.x;
    int wid = (blockIdx.x & 7) * (nwg >> 3) + (blockIdx.x >> 3);   // XCD-chunked swizzle
    int MT  = nwg >> 5;                 // NT = 32
    int mtl = wid % MT;
    int nt  = wid / MT;

    int slot_tile = chunk_start + mtl * 128;
    if (slot_tile >= pbase[NE]) return;
    int e = find_expert(pbase, slot_tile);
    int cnt = counts[e];
    int loc_tile = slot_tile - pbase[e];
    if (loc_tile >= cnt) return;

    int t = threadIdx.x;
    int lane = t & 63, wave = t >> 6;

    // A gather staging: 2 threads/row, 32 fp32 each -> 32 bf16
    int am = t >> 1, ahalf = (t & 1) * 32;
    int localc = loc_tile + am; if (localc > cnt - 1) localc = cnt - 1;
    int tok = idx_list[e * CAP + localc];
    const float* arow = x + (size_t)tok * DM + ahalf;
    __bf16* adst = Alds + am * 72 + ahalf;

    // B gload_lds staging: 4 segments/wave; row = wave*32+q*8+(lane>>3), chunk = lane&7
    int brow_b = wave * 32 + (lane >> 3);
    int bchunk = lane & 7;
    const char* bsrc[4];
    char* bdst[4];
#pragma unroll
    for (int q = 0; q < 4; ++q) {
        int row = brow_b + q * 8;
        bsrc[q] = (const char*)(w1t + ((size_t)e * FFNDIM + nt * 128 + row) * DM)
                  + ((bchunk ^ (row & 7)) << 4);
        bdst[q] = (char*)Blds + (wave * 4 + q) * 1024;   // wave-uniform
    }

    int wm = (wave >> 1) * 64, wn = (wave & 1) * 64;
    int l15 = lane & 15, quad = lane >> 4;

    f32x4 acc[4][4];
#pragma unroll
    for (int i = 0; i < 4; ++i)
#pragma unroll
        for (int j = 0; j < 4; ++j) acc[i][j] = f32x4{0.f, 0.f, 0.f, 0.f};

    for (int kb = 0; kb < DM; kb += 64) {
        f32x4 av[8];
        const f32x4* ap = (const f32x4*)(arow + kb);
#pragma unroll
        for (int q = 0; q < 8; ++q) av[q] = ap[q];
        uint4 apk[4];
#pragma unroll
        for (int q = 0; q < 4; ++q) {
            PK8 u;
#pragma unroll
            for (int w = 0; w < 4; ++w) {
                u.h[w]     = (__bf16)av[2 * q][w];
                u.h[4 + w] = (__bf16)av[2 * q + 1][w];
            }
            apk[q] = u.v;
        }
        __syncthreads();                                 // prev iter's LDS reads done
#pragma unroll
        for (int q = 0; q < 4; ++q) gload16(bsrc[q] + kb * 2, bdst[q]);
#pragma unroll
        for (int q = 0; q < 4; ++q) *(uint4*)(adst + q * 8) = apk[q];
        __syncthreads();                                 // drains vmcnt + lgkmcnt
#pragma unroll
        for (int ks = 0; ks < 2; ++ks) {
            int ko = ks * 32 + quad * 8;
            int kc = ks * 4 + quad;                      // 16B chunk index
            bf16x8 af[4], bfr[4];
#pragma unroll
            for (int i = 0; i < 4; ++i)
                af[i] = *(const bf16x8*)(Alds + (wm + i * 16 + l15) * 72 + ko);
#pragma unroll
            for (int j = 0; j < 4; ++j) {
                int n = wn + j * 16 + l15;
                bfr[j] = *(const bf16x8*)(Blds + n * 64 + ((kc ^ (n & 7)) << 3));
            }
#pragma unroll
            for (int i = 0; i < 4; ++i)
#pragma unroll
                for (int j = 0; j < 4; ++j)
                    acc[i][j] = __builtin_amdgcn_mfma_f32_16x16x32_bf16(
                        af[i], bfr[j], acc[i][j], 0, 0, 0);
        }
    }
    float bias[4];
#pragma unroll
    for (int j = 0; j < 4; ++j)
        bias[j] = b1[(size_t)e * FFNDIM + nt * 128 + wn + j * 16 + l15];
#pragma unroll
    for (int i = 0; i < 4; ++i) {
#pragma unroll
        for (int r = 0; r < 4; ++r) {
            int rowl = wm + i * 16 + quad * 4 + r;       // C/D: col=lane&15, row=quad*4+reg
            if (loc_tile + rowl < cnt) {
                size_t hoff = (size_t)(mtl * 128 + rowl) * FFNDIM + nt * 128;
#pragma unroll
                for (int j = 0; j < 4; ++j) {
                    float v = acc[i][j][r] + bias[j];
                    h[hoff + wn + j * 16 + l15] = (__bf16)gelu_exact(v);
                }
            }
        }
    }
}

// ---------------- gemm2: y[slot] = gate*(h_slot @ w2[e] + b2)  (or atomic out fallback) ----------------
// A: gload_lds from h (bf16, chunk-local contiguous rows; padding rows read garbage ->
// confined to their own acc rows, never written). B: gload_lds from w2t [e][n][k].
// YM: 0 = atomicAdd to out (K-split allowed), 1 = f32 ybuf, 2 = bf16 ybuf.
template<int YM>
__global__ __launch_bounds__(256, 4) void gemm2_kernel(
        const __bf16* __restrict__ h, const __bf16* __restrict__ w2t,
        const float* __restrict__ b2, const int* __restrict__ counts,
        const int* __restrict__ pbase, const int* __restrict__ idx_list,
        const float* __restrict__ gate_list, float* __restrict__ out,
        void* __restrict__ ybuf, int ksp_count, int chunk_start) {
    __shared__ __bf16 Alds[128 * 64];
    __shared__ __bf16 Blds[128 * 64];

    int nwg = gridDim.x;
    int wid = (blockIdx.x & 7) * (nwg >> 3) + (blockIdx.x >> 3);
    int MT  = nwg / (8 * ksp_count);
    int mtl = wid % MT;
    int nt  = (wid / MT) & 7;
    int ksp = wid / (MT * 8);
    int kspan = FFNDIM / ksp_count;

    int slot_tile = chunk_start + mtl * 128;
    if (slot_tile >= pbase[NE]) return;
    int e = find_expert(pbase, slot_tile);
    int cnt = counts[e];
    int loc_tile = slot_tile - pbase[e];
    if (loc_tile >= cnt) return;

    int t = threadIdx.x;
    int lane = t & 63, wave = t >> 6;

    int row_b = wave * 32 + (lane >> 3);
    int chnk = lane & 7;
    const char* asrc[4];
    const char* bsrc[4];
    char* adst[4];
    char* bdst[4];
#pragma unroll
    for (int q = 0; q < 4; ++q) {
        int row = row_b + q * 8;
        int sw = ((chnk ^ (row & 7)) << 4);
        asrc[q] = (const char*)(h + (size_t)(mtl * 128 + row) * FFNDIM
                                + (size_t)ksp * kspan) + sw;
        bsrc[q] = (const char*)(w2t + ((size_t)e * DM + nt * 128 + row) * FFNDIM
                                + (size_t)ksp * kspan) + sw;
        adst[q] = (char*)Alds + (wave * 4 + q) * 1024;
        bdst[q] = (char*)Blds + (wave * 4 + q) * 1024;
    }

    int wm = (wave >> 1) * 64, wn = (wave & 1) * 64;
    int l15 = lane & 15, quad = lane >> 4;

    f32x4 acc[4][4];
#pragma unroll
    for (int i = 0; i < 4; ++i)
#pragma unroll
        for (int j = 0; j < 4; ++j) acc[i][j] = f32x4{0.f, 0.f, 0.f, 0.f};

    for (int kb = 0; kb < kspan; kb += 64) {
        __syncthreads();
#pragma unroll
        for (int q = 0; q < 4; ++q) gload16(asrc[q] + kb * 2, adst[q]);
#pragma unroll
        for (int q = 0; q < 4; ++q) gload16(bsrc[q] + kb * 2, bdst[q]);
        __syncthreads();
#pragma unroll
        for (int ks = 0; ks < 2; ++ks) {
            int ko = ks * 32 + quad * 8;
            int kc = ks * 4 + quad;
            bf16x8 af[4], bfr[4];
#pragma unroll
            for (int i = 0; i < 4; ++i) {
                int m = wm + i * 16 + l15;
                af[i] = *(const bf16x8*)(Alds + m * 64 + ((kc ^ (m & 7)) << 3));
            }
#pragma unroll
            for (int j = 0; j < 4; ++j) {
                int n = wn + j * 16 + l15;
                bfr[j] = *(const bf16x8*)(Blds + n * 64 + ((kc ^ (n & 7)) << 3));
            }
#pragma unroll
            for (int i = 0; i < 4; ++i)
#pragma unroll
                for (int j = 0; j < 4; ++j)
                    acc[i][j] = __builtin_amdgcn_mfma_f32_16x16x32_bf16(
                        af[i], bfr[j], acc[i][j], 0, 0, 0);
        }
    }
    float b2v[4];
#pragma unroll
    for (int j = 0; j < 4; ++j)
        b2v[j] = b2[(size_t)e * DM + nt * 128 + wn + j * 16 + l15];
#pragma unroll
    for (int i = 0; i < 4; ++i) {
#pragma unroll
        for (int r = 0; r < 4; ++r) {
            int rowl = wm + i * 16 + quad * 4 + r;
            int local = loc_tile + rowl;
            if (local < cnt) {
                float g = gate_list[e * CAP + local];
                if (YM == 0) {
                    int tok = idx_list[e * CAP + local];
                    float* orow = out + (size_t)tok * DM + nt * 128;
#pragma unroll
                    for (int j = 0; j < 4; ++j) {
                        float v = acc[i][j][r];
                        if (ksp == 0) v += b2v[j];
                        atomicAdd(orow + wn + j * 16 + l15, g * v);
                    }
                } else {
                    size_t yoff = (size_t)(slot_tile + rowl) * DM + nt * 128;
                    if (YM == 1) {
                        float* yr = (float*)ybuf + yoff;
#pragma unroll
                        for (int j = 0; j < 4; ++j)
                            yr[wn + j * 16 + l15] = g * (acc[i][j][r] + b2v[j]);
                    } else {
                        __bf16* yr = (__bf16*)ybuf + yoff;
#pragma unroll
                        for (int j = 0; j < 4; ++j)
                            yr[wn + j * 16 + l15] = (__bf16)(g * (acc[i][j][r] + b2v[j]));
                    }
                }
            }
        }
    }
}

// ---------------- combine: out[tok] = y[slot0] + y[slot1] ----------------
template<int YM>
__global__ __launch_bounds__(256) void combine_kernel(
        const void* __restrict__ ybuf, const uint32_t* __restrict__ pack,
        const int* __restrict__ pbase, float* __restrict__ out) {
    int tk = blockIdx.x;
    uint32_t pk = pack[tk];
    uint32_t a = pk >> 16, b = pk & 0xffffu;
    size_t sa = (size_t)pbase[a >> 13] + (a & 8191u);
    size_t sb = (size_t)pbase[b >> 13] + (b & 8191u);
    int d = threadIdx.x * 4;
    f32x4 vo;
    if (YM == 1) {
        const float* y = (const float*)ybuf;
        f32x4 va = *(const f32x4*)(y + sa * DM + d);
        f32x4 vb = *(const f32x4*)(y + sb * DM + d);
#pragma unroll
        for (int j = 0; j < 4; ++j) vo[j] = va[j] + vb[j];
    } else {
        const __bf16* y = (const __bf16*)ybuf;
        bf16x4 va = *(const bf16x4*)(y + sa * DM + d);
        bf16x4 vb = *(const bf16x4*)(y + sb * DM + d);
#pragma unroll
        for (int j = 0; j < 4; ++j) vo[j] = (float)va[j] + (float)vb[j];
    }
    *(f32x4*)(out + (size_t)tk * DM + d) = vo;
}

extern "C" void kernel_launch(void* const* d_in, const int* in_sizes, int n_in,
                              void* d_out, int out_size, void* d_ws, size_t ws_size,
                              hipStream_t stream) {
    const float* x      = (const float*)d_in[0];
    const float* gate_w = (const float*)d_in[1];
    const float* gate_b = (const float*)d_in[2];
    const float* w1     = (const float*)d_in[3];
    const float* b1     = (const float*)d_in[4];
    const float* w2     = (const float*)d_in[5];
    const float* b2     = (const float*)d_in[6];
    float* out = (float*)d_out;

    // ws: [counts 64][pbase 64][idx 256K][gate 256K][pack 32K][w1t 64M][w2t 64M][ybuf][hbuf]
    char* wsb = (char*)d_ws;
    int*      counts   = (int*)wsb;
    int*      pbase    = (int*)(wsb + 64);
    int*      idx_list = (int*)(wsb + 128);
    float*    gate_lst = (float*)(wsb + 128 + 262144);
    uint32_t* pack     = (uint32_t*)(wsb + 128 + 524288);
    const size_t FIXED = 557184;
    const size_t W_ELEMS = (size_t)NE * DM * FFNDIM;     // 33,554,432 bf16 each
    __bf16* w1t = (__bf16*)(wsb + FIXED);
    __bf16* w2t = w1t + W_ELEMS;
    char*   dyn = (char*)(w2t + W_ELEMS);                // FIXED + 128 MiB
    const size_t DYNBASE = FIXED + 4 * W_ELEMS;
    size_t avail = ws_size > DYNBASE ? ws_size - DYNBASE : 0;

    const size_t YB32 = 17408ull * DM * 4;               // slot-global ybuf (full range)
    const size_t YB16 = 17408ull * DM * 2;
    int S, NCH, YM, KSP;
    if      (avail >= YB32 + 17408ull * 8192) { S = 17408; NCH = 1;  YM = 1; KSP = 1; }
    else if (avail >= YB32 + 4096ull * 8192)  { S = 4096;  NCH = 5;  YM = 1; KSP = 1; }
    else if (avail >= YB16 + 4096ull * 8192)  { S = 4096;  NCH = 5;  YM = 2; KSP = 1; }
    else if (avail >= YB16 + 2048ull * 8192)  { S = 2048;  NCH = 9;  YM = 2; KSP = 1; }
    else                                      { S = 512;   NCH = 34; YM = 0; KSP = 8; }
    char*   ybuf = dyn;
    __bf16* hbuf = (__bf16*)(dyn + (YM == 1 ? YB32 : YM == 2 ? YB16 : 0));

    transpose_cvt_kernel<<<dim3(FFNDIM / 64, DM / 64, NE), 256, 0, stream>>>(
        w1, w1t, DM, FFNDIM);
    transpose_cvt_kernel<<<dim3(DM / 64, FFNDIM / 64, NE), 256, 0, stream>>>(
        w2, w2t, FFNDIM, DM);
    if (YM) zero_counts_kernel<<<1, 64, 0, stream>>>(counts);
    else    zero_out_kernel<<<4096, 256, 0, stream>>>(out, counts);
    router_kernel<<<2048, 256, 0, stream>>>(x, gate_w, gate_b, counts, idx_list,
                                            gate_lst, pack);
    scan_kernel<<<1, 64, 0, stream>>>(counts, pbase);

    int MT = S / 128;
    for (int c = 0; c < NCH; ++c) {
        gemm1_kernel<<<dim3(MT * 32), 256, 0, stream>>>(x, w1t, b1, counts, pbase,
                                                        idx_list, hbuf, c * S);
        if (YM == 1)
            gemm2_kernel<1><<<dim3(MT * 8), 256, 0, stream>>>(
                hbuf, w2t, b2, counts, pbase, idx_list, gate_lst, out, ybuf, 1, c * S);
        else if (YM == 2)
            gemm2_kernel<2><<<dim3(MT * 8), 256, 0, stream>>>(
                hbuf, w2t, b2, counts, pbase, idx_list, gate_lst, out, ybuf, 1, c * S);
        else
            gemm2_kernel<0><<<dim3(MT * 8 * KSP), 256, 0, stream>>>(
                hbuf, w2t, b2, counts, pbase, idx_list, gate_lst, out, ybuf, KSP, c * S);
    }
    if (YM == 1)
        combine_kernel<1><<<dim3(T_TOKENS), 256, 0, stream>>>(ybuf, pack, pbase, out);
    else if (YM == 2)
        combine_kernel<2><<<dim3(T_TOKENS), 256, 0, stream>>>(ybuf, pack, pbase, out);
}